// Round 1
// baseline (377.717 us; speedup 1.0000x reference)
//
#include <hip/hip_runtime.h>

#define VDIM 20000
#define EDIM 128
#define BATCH 64
#define SEQ 100
#define NVT 157  // ceil(VDIM/128)

typedef float f32x4 __attribute__((ext_vector_type(4)));
typedef short bf16x8 __attribute__((ext_vector_type(8)));
typedef unsigned short ushortx8 __attribute__((ext_vector_type(8)));

__device__ __forceinline__ unsigned short f2bf(float f) {
  unsigned u = __builtin_bit_cast(unsigned, f);
  u += 0x7FFFu + ((u >> 16) & 1u);   // RTNE
  return (unsigned short)(u >> 16);
}

// ---------------- prep 1: W_item/W_user fp32 -> bf16 in ws ----------------
__global__ void wconv_kernel(const float* __restrict__ Wi, const float* __restrict__ Wu,
                             unsigned short* __restrict__ wbf) {
  const int c = blockIdx.y;
  const float* src = c ? Wu : Wi;
  unsigned short* dst = wbf + (size_t)c * (VDIM * EDIM);
  const int i0 = (blockIdx.x * 256 + threadIdx.x) * 8;
  float4 a = *(const float4*)(src + i0);
  float4 b = *(const float4*)(src + i0 + 4);
  ushortx8 o;
  o[0] = f2bf(a.x); o[1] = f2bf(a.y); o[2] = f2bf(a.z); o[3] = f2bf(a.w);
  o[4] = f2bf(b.x); o[5] = f2bf(b.y); o[6] = f2bf(b.z); o[7] = f2bf(b.w);
  *(ushortx8*)(dst + i0) = o;
}

// ---------------- prep 2: gather A blocks [2][64][128][128] bf16 ----------
// rows 0..99 = W_c[attr[b,s]]; row 100 = direct embedding; rows 101..127 = 0
__global__ void gather_kernel(const int* __restrict__ attr_item, const int* __restrict__ attr_user,
                              const int* __restrict__ item_ids, const int* __restrict__ user_ids,
                              const float* __restrict__ W_item, const float* __restrict__ W_user,
                              const float* __restrict__ item_emb, const float* __restrict__ user_emb,
                              unsigned short* __restrict__ abf) {
  const int b = blockIdx.x, c = blockIdx.y;
  const int t = threadIdx.x;
  const int r = t >> 1, h = t & 1;        // 2 threads per row, 64 cols each
  const int* ids = c ? attr_user : attr_item;
  const float* W = c ? W_user : W_item;
  const float* demb = c ? user_emb : item_emb;
  const int* dids = c ? user_ids : item_ids;
  unsigned short* dst = abf + (((size_t)(c * BATCH + b) * 128 + r) * EDIM) + h * 64;
  const float* src = nullptr;
  if (r < SEQ)       src = W + (size_t)ids[b * SEQ + r] * EDIM + h * 64;
  else if (r == SEQ) src = demb + (size_t)dids[b] * EDIM + h * 64;
  if (src) {
    #pragma unroll
    for (int i = 0; i < 8; ++i) {
      float4 a  = *(const float4*)(src + i * 8);
      float4 bb = *(const float4*)(src + i * 8 + 4);
      ushortx8 o;
      o[0] = f2bf(a.x);  o[1] = f2bf(a.y);  o[2] = f2bf(a.z);  o[3] = f2bf(a.w);
      o[4] = f2bf(bb.x); o[5] = f2bf(bb.y); o[6] = f2bf(bb.z); o[7] = f2bf(bb.w);
      *(ushortx8*)(dst + i * 8) = o;
    }
  } else {
    ushortx8 z = {0, 0, 0, 0, 0, 0, 0, 0};
    #pragma unroll
    for (int i = 0; i < 8; ++i) *(ushortx8*)(dst + i * 8) = z;
  }
}

// ---------------- main: per (b, vtile) GEMM + fused softmax epilogue ------
// LDS: sA (32KB, XOR-swizzled 128x128 bf16) + sB (32KB, same). Partial
// reduction arrays overlay the sB region after the GEMM reads complete.
__global__ __launch_bounds__(256, 2) void main_kernel(
    const unsigned short* __restrict__ wbf, const unsigned short* __restrict__ abf,
    const float* __restrict__ tf_item, const int* __restrict__ lens_item,
    const float* __restrict__ tf_user, const int* __restrict__ lens_user,
    float* __restrict__ out) {
  __shared__ __align__(16) unsigned char lds[65536];
  float* sDen = (float*)(lds + 32768);          // [2][128]
  float* sNum = (float*)(lds + 32768 + 1024);   // [2][128]
  float* sDir = (float*)(lds + 32768 + 2048);   // [2][128]

  const int b = blockIdx.x, vt = blockIdx.y;
  const int v0 = vt * 128;
  const int t = threadIdx.x;
  const int lane = t & 63, wave = t >> 6;
  const int wm = wave >> 1, wn = wave & 1;      // 2x2 wave grid
  const int quad = lane >> 4, l15 = lane & 15;

  float res = 0.f;                              // owned by t<128 (col t)

  for (int c = 0; c < 2; ++c) {
    if (c) __syncthreads();  // protect overlay reads before restaging

    // ---- stage A tile (128x128 bf16, swizzled) ----
    const uint4* gA = (const uint4*)(abf + ((size_t)(c * BATCH + b) * 128) * EDIM);
    #pragma unroll
    for (int i = 0; i < 8; ++i) {
      int chunk = t + 256 * i;                  // 2048 x 16B
      int r = chunk >> 4, j = chunk & 15;
      uint4 val = gA[chunk];
      *(uint4*)(lds + r * 256 + ((j ^ (r & 15)) << 4)) = val;
    }
    // ---- stage B tile (W rows v0..v0+127, swizzled, zero-fill OOB) ----
    const unsigned short* gW = wbf + (size_t)c * (VDIM * EDIM);
    #pragma unroll
    for (int i = 0; i < 8; ++i) {
      int chunk = t + 256 * i;
      int r = chunk >> 4, j = chunk & 15;
      int v = v0 + r;
      uint4 val = make_uint4(0u, 0u, 0u, 0u);
      if (v < VDIM) val = *(const uint4*)(gW + (size_t)v * EDIM + j * 8);
      *(uint4*)(lds + 32768 + r * 256 + ((j ^ (r & 15)) << 4)) = val;
    }
    __syncthreads();

    // ---- GEMM: wave computes 64x64 (Mt4 x Nt4 x Ks4 of 16x16x32) ----
    f32x4 acc[4][4];
    #pragma unroll
    for (int mt = 0; mt < 4; ++mt)
      #pragma unroll
      for (int nt = 0; nt < 4; ++nt) {
        f32x4 z = {0.f, 0.f, 0.f, 0.f};
        acc[mt][nt] = z;
      }
    #pragma unroll
    for (int ks = 0; ks < 4; ++ks) {
      const int j = ks * 4 + quad;
      bf16x8 af[4], bfr[4];
      #pragma unroll
      for (int mt = 0; mt < 4; ++mt) {
        int row = wm * 64 + mt * 16 + l15;
        af[mt] = *(const bf16x8*)(lds + row * 256 + ((j ^ (row & 15)) << 4));
      }
      #pragma unroll
      for (int nt = 0; nt < 4; ++nt) {
        int col = wn * 64 + nt * 16 + l15;
        bfr[nt] = *(const bf16x8*)(lds + 32768 + col * 256 + ((j ^ (col & 15)) << 4));
      }
      #pragma unroll
      for (int mt = 0; mt < 4; ++mt)
        #pragma unroll
        for (int nt = 0; nt < 4; ++nt)
          acc[mt][nt] = __builtin_amdgcn_mfma_f32_16x16x32_bf16(af[mt], bfr[nt], acc[mt][nt], 0, 0, 0);
    }
    __syncthreads();  // all lanes done reading sA/sB before overlay writes

    // ---- epilogue: softmax-weighted reduction over s, + direct row ----
    const float* tf = c ? tf_user : tf_item;
    const int* lensp = c ? lens_user : lens_item;
    const int lenb = lensp[b];
    float wv[4][4];
    #pragma unroll
    for (int mt = 0; mt < 4; ++mt)
      #pragma unroll
      for (int r = 0; r < 4; ++r) {
        int row = wm * 64 + mt * 16 + quad * 4 + r;
        wv[mt][r] = (row < SEQ) ? (tf[b * SEQ + row] * ((row < lenb) ? 1.f : 0.f)) : 0.f;
      }
    #pragma unroll
    for (int nt = 0; nt < 4; ++nt) {
      float den = 0.f, num = 0.f, dir = 0.f;
      #pragma unroll
      for (int mt = 0; mt < 4; ++mt)
        #pragma unroll
        for (int r = 0; r < 4; ++r) {
          int row = wm * 64 + mt * 16 + quad * 4 + r;
          float v = acc[mt][nt][r];
          if (row < SEQ) {
            float e = __expf(v);
            den += e;
            num += wv[mt][r] * e * v;
          } else if (row == SEQ) {
            dir = v;
          }
        }
      den += __shfl_xor(den, 16, 64); den += __shfl_xor(den, 32, 64);
      num += __shfl_xor(num, 16, 64); num += __shfl_xor(num, 32, 64);
      dir += __shfl_xor(dir, 16, 64); dir += __shfl_xor(dir, 32, 64);
      if (quad == 0) {
        int col = wn * 64 + nt * 16 + l15;
        sDen[wm * 128 + col] = den;
        sNum[wm * 128 + col] = num;
        sDir[wm * 128 + col] = dir;
      }
    }
    __syncthreads();
    if (t < 128) {
      float den = sDen[t] + sDen[128 + t];
      float num = sNum[t] + sNum[128 + t];
      float dir = sDir[t] + sDir[128 + t];
      res += num / den + dir;
    }
  }

  if (t < 128) {
    int v = v0 + t;
    if (v < VDIM) out[(size_t)b * VDIM + v] = res;
  }
}

extern "C" void kernel_launch(void* const* d_in, const int* in_sizes, int n_in,
                              void* d_out, int out_size, void* d_ws, size_t ws_size,
                              hipStream_t stream) {
  const int*   attr_item = (const int*)d_in[0];
  const float* tf_item   = (const float*)d_in[1];
  const int*   lens_item = (const int*)d_in[2];
  const int*   item_ids  = (const int*)d_in[3];
  const int*   attr_user = (const int*)d_in[4];
  const float* tf_user   = (const float*)d_in[5];
  const int*   lens_user = (const int*)d_in[6];
  const int*   user_ids  = (const int*)d_in[7];
  const float* W_item    = (const float*)d_in[8];
  const float* W_user    = (const float*)d_in[9];
  const float* user_emb  = (const float*)d_in[10];
  const float* item_emb  = (const float*)d_in[11];
  float* out = (float*)d_out;

  unsigned short* wbf = (unsigned short*)d_ws;                  // [2][V][E] bf16
  unsigned short* abf = wbf + (size_t)2 * VDIM * EDIM;          // [2][64][128][E] bf16

  wconv_kernel<<<dim3(VDIM * EDIM / (256 * 8), 2), 256, 0, stream>>>(W_item, W_user, wbf);
  gather_kernel<<<dim3(BATCH, 2), 256, 0, stream>>>(attr_item, attr_user, item_ids, user_ids,
                                                    W_item, W_user, item_emb, user_emb, abf);
  main_kernel<<<dim3(BATCH, NVT), 256, 0, stream>>>(wbf, abf, tf_item, lens_item,
                                                    tf_user, lens_user, out);
}

// Round 2
// 363.522 us; speedup vs baseline: 1.0391x; 1.0391x over previous
//
#include <hip/hip_runtime.h>

#define VDIM 20000
#define EDIM 128
#define BATCH 64
#define SEQ 100
#define BN 256
#define NVT 79   // ceil(20000/256)
#define NBG 16   // groups of 4 b's

typedef float f32x4 __attribute__((ext_vector_type(4)));
typedef short bf16x8 __attribute__((ext_vector_type(8)));
typedef unsigned short ushortx8 __attribute__((ext_vector_type(8)));

__device__ __forceinline__ unsigned short f2bf(float f) {
  unsigned u = __builtin_bit_cast(unsigned, f);
  u += 0x7FFFu + ((u >> 16) & 1u);   // RTNE
  return (unsigned short)(u >> 16);
}

// ---- fused prep: W->bf16 conversion (blocks 0..1249) + A gather (1250..1377)
__global__ void prep_kernel(const float* __restrict__ Wi, const float* __restrict__ Wu,
                            const int* __restrict__ attr_item, const int* __restrict__ attr_user,
                            const int* __restrict__ item_ids, const int* __restrict__ user_ids,
                            const float* __restrict__ item_emb, const float* __restrict__ user_emb,
                            unsigned short* __restrict__ wbf, unsigned short* __restrict__ abf) {
  const int bid = blockIdx.x, t = threadIdx.x;
  if (bid < 1250) {
    const int i0 = (bid * 256 + t) * 8;
    #pragma unroll
    for (int c = 0; c < 2; ++c) {
      const float* src = c ? Wu : Wi;
      unsigned short* dst = wbf + (size_t)c * (VDIM * EDIM);
      float4 a = *(const float4*)(src + i0);
      float4 b = *(const float4*)(src + i0 + 4);
      ushortx8 o;
      o[0] = f2bf(a.x); o[1] = f2bf(a.y); o[2] = f2bf(a.z); o[3] = f2bf(a.w);
      o[4] = f2bf(b.x); o[5] = f2bf(b.y); o[6] = f2bf(b.z); o[7] = f2bf(b.w);
      *(ushortx8*)(dst + i0) = o;
    }
  } else {
    const int g = bid - 1250;
    const int b = g & 63, c = g >> 6;
    const int r = t >> 1, h = t & 1;
    const int* ids = c ? attr_user : attr_item;
    const float* W = c ? Wu : Wi;
    const float* demb = c ? user_emb : item_emb;
    const int* dids = c ? user_ids : item_ids;
    unsigned short* dst = abf + (((size_t)(c * BATCH + b) * 128 + r) * EDIM) + h * 64;
    const float* src = nullptr;
    if (r < SEQ)       src = W + (size_t)ids[b * SEQ + r] * EDIM + h * 64;
    else if (r == SEQ) src = demb + (size_t)dids[b] * EDIM + h * 64;
    if (src) {
      #pragma unroll
      for (int i = 0; i < 8; ++i) {
        float4 a  = *(const float4*)(src + i * 8);
        float4 bb = *(const float4*)(src + i * 8 + 4);
        ushortx8 o;
        o[0] = f2bf(a.x);  o[1] = f2bf(a.y);  o[2] = f2bf(a.z);  o[3] = f2bf(a.w);
        o[4] = f2bf(bb.x); o[5] = f2bf(bb.y); o[6] = f2bf(bb.z); o[7] = f2bf(bb.w);
        *(ushortx8*)(dst + i * 8) = o;
      }
    } else {
      ushortx8 z = {0, 0, 0, 0, 0, 0, 0, 0};
      #pragma unroll
      for (int i = 0; i < 8; ++i) *(ushortx8*)(dst + i * 8) = z;
    }
  }
}

// ---- main: per (vtile256, bgroup4): B staged once/cluster, 2 b's per stage
__global__ __launch_bounds__(512, 2) void main_kernel(
    const unsigned short* __restrict__ wbf, const unsigned short* __restrict__ abf,
    const float* __restrict__ tf_item, const int* __restrict__ lens_item,
    const float* __restrict__ tf_user, const int* __restrict__ lens_user,
    float* __restrict__ out) {
  __shared__ __align__(16) unsigned char sA[65536];   // 2 b x 128 rows x 256B (swizzled)
  __shared__ __align__(16) unsigned char sB[65536];   // 256 v-rows x 256B (swizzled)
  __shared__ float sWV[256];                           // [2b][128] tf*lenmask
  __shared__ float sDen[2][2][2][256];                 // [b][wm][quadpair][col]
  __shared__ float sNum[2][2][2][256];
  __shared__ float sDir[2][256];

  const int t = threadIdx.x;
  const int v0 = blockIdx.x * BN;
  const int bg4 = blockIdx.y * 4;
  const int lane = t & 63, wave = t >> 6;
  const int bl = wave >> 2, wm = (wave >> 1) & 1, wn = wave & 1;
  const int quad = lane >> 4, l15 = lane & 15;
  const int cb = t >> 8, cc = t & 255;   // combine/store ownership

  const uint4* abfq = (const uint4*)abf;
  const uint4* wbfq = (const uint4*)wbf;

  float res[2] = {0.f, 0.f};
  uint4 pa[8];

  // prefetch A for stage 0 (c=0, it=0 -> b = bg4+0, bg4+1)
  #pragma unroll
  for (int i = 0; i < 8; ++i) {
    int ch = t + 512 * i, r = ch >> 4, j = ch & 15;
    int b = bg4 + (r >> 7);
    pa[i] = abfq[((size_t)b * 128 + (r & 127)) * 16 + j];
  }

  #pragma unroll 1
  for (int s = 0; s < 4; ++s) {
    const int c = s >> 1, it = s & 1;

    // write prefetched A tile (2 b's) into LDS, swizzled
    #pragma unroll
    for (int i = 0; i < 8; ++i) {
      int ch = t + 512 * i, r = ch >> 4, j = ch & 15;
      *(uint4*)(sA + r * 256 + ((j ^ (r & 15)) << 4)) = pa[i];
    }
    // stage tf*mask weights
    if (t < 256) {
      int row = t & 127;
      int b = bg4 + it * 2 + (t >> 7);
      const float* tf = c ? tf_user : tf_item;
      const int* ln = c ? lens_user : lens_item;
      float w = 0.f;
      if (row < ln[b]) w = tf[b * SEQ + row];   // len<=100 => row<100, safe
      sWV[t] = w;
    }
    // stage B once per cluster
    if (it == 0) {
      #pragma unroll
      for (int i = 0; i < 8; ++i) {
        int ch = t + 512 * i, r = ch >> 4, j = ch & 15;
        int v = v0 + r;
        uint4 val = make_uint4(0u, 0u, 0u, 0u);
        if (v < VDIM) val = wbfq[(size_t)c * 320000 + (size_t)v * 16 + j];
        *(uint4*)(sB + r * 256 + ((j ^ (r & 15)) << 4)) = val;
      }
    }
    __syncthreads();

    // ---- GEMM: wave = (b=bl) 64x128 tile: Mt4 x Nt8, Ks4 of 16x16x32 ----
    f32x4 acc[4][8];
    #pragma unroll
    for (int mt = 0; mt < 4; ++mt)
      #pragma unroll
      for (int nt = 0; nt < 8; ++nt) { f32x4 z = {0.f,0.f,0.f,0.f}; acc[mt][nt] = z; }

    const unsigned char* pAb = sA + (bl * 128 + wm * 64) * 256;
    const unsigned char* pBb = sB + (wn * 128) * 256;
    #pragma unroll
    for (int ks = 0; ks < 4; ++ks) {
      const int j = ks * 4 + quad;
      const int sw = (j ^ l15) << 4;
      bf16x8 af[4], bfr[8];
      #pragma unroll
      for (int mt = 0; mt < 4; ++mt)
        af[mt] = *(const bf16x8*)(pAb + (mt * 16 + l15) * 256 + sw);
      #pragma unroll
      for (int nt = 0; nt < 8; ++nt)
        bfr[nt] = *(const bf16x8*)(pBb + (nt * 16 + l15) * 256 + sw);
      #pragma unroll
      for (int mt = 0; mt < 4; ++mt)
        #pragma unroll
        for (int nt = 0; nt < 8; ++nt)
          acc[mt][nt] = __builtin_amdgcn_mfma_f32_16x16x32_bf16(af[mt], bfr[nt], acc[mt][nt], 0, 0, 0);
    }

    // prefetch next stage's A tile while epilogue runs
    if (s < 3) {
      const int nc = (s + 1) >> 1, nit = (s + 1) & 1;
      #pragma unroll
      for (int i = 0; i < 8; ++i) {
        int ch = t + 512 * i, r = ch >> 4, j = ch & 15;
        int b = bg4 + nit * 2 + (r >> 7);
        pa[i] = abfq[((size_t)(nc * BATCH + b) * 128 + (r & 127)) * 16 + j];
      }
    }

    // ---- epilogue: den/num partials (no pad masks; corrected in combine) --
    float wvr[4][4];
    #pragma unroll
    for (int mt = 0; mt < 4; ++mt)
      #pragma unroll
      for (int r = 0; r < 4; ++r)
        wvr[mt][r] = sWV[bl * 128 + wm * 64 + mt * 16 + quad * 4 + r];

    #pragma unroll
    for (int nt = 0; nt < 8; ++nt) {
      float den = 0.f, num = 0.f;
      #pragma unroll
      for (int mt = 0; mt < 4; ++mt)
        #pragma unroll
        for (int r = 0; r < 4; ++r) {
          float v = acc[mt][nt][r];
          float e = __expf(v);
          den += e;
          num = fmaf(wvr[mt][r], e * v, num);
        }
      den += __shfl_xor(den, 16, 64);
      num += __shfl_xor(num, 16, 64);
      const int col = wn * 128 + nt * 16 + l15;
      if (!(quad & 1)) {
        sDen[bl][wm][quad >> 1][col] = den;
        sNum[bl][wm][quad >> 1][col] = num;
      }
      if (wm == 1 && quad == 1) sDir[bl][col] = acc[2][nt][0];  // row 100
    }
    __syncthreads();

    // ---- combine: each thread owns (b=cb, col=cc) ----
    {
      float den = sDen[cb][0][0][cc] + sDen[cb][0][1][cc] + sDen[cb][1][0][cc] + sDen[cb][1][1][cc];
      float num = sNum[cb][0][0][cc] + sNum[cb][0][1][cc] + sNum[cb][1][0][cc] + sNum[cb][1][1][cc];
      float dir = sDir[cb][cc];
      den -= 27.f + __expf(dir);   // remove 27 zero-pad rows + the dir row
      res[it] += num / den + dir;
    }
  }

  #pragma unroll
  for (int it = 0; it < 2; ++it) {
    int b = bg4 + it * 2 + cb;
    int v = v0 + cc;
    if (v < VDIM) out[(size_t)b * VDIM + v] = res[it];
  }
}

extern "C" void kernel_launch(void* const* d_in, const int* in_sizes, int n_in,
                              void* d_out, int out_size, void* d_ws, size_t ws_size,
                              hipStream_t stream) {
  const int*   attr_item = (const int*)d_in[0];
  const float* tf_item   = (const float*)d_in[1];
  const int*   lens_item = (const int*)d_in[2];
  const int*   item_ids  = (const int*)d_in[3];
  const int*   attr_user = (const int*)d_in[4];
  const float* tf_user   = (const float*)d_in[5];
  const int*   lens_user = (const int*)d_in[6];
  const int*   user_ids  = (const int*)d_in[7];
  const float* W_item    = (const float*)d_in[8];
  const float* W_user    = (const float*)d_in[9];
  const float* user_emb  = (const float*)d_in[10];
  const float* item_emb  = (const float*)d_in[11];
  float* out = (float*)d_out;

  unsigned short* wbf = (unsigned short*)d_ws;                  // [2][V][E] bf16
  unsigned short* abf = wbf + (size_t)2 * VDIM * EDIM;          // [2][64][128][E] bf16

  prep_kernel<<<dim3(1250 + 128), 256, 0, stream>>>(W_item, W_user, attr_item, attr_user,
                                                    item_ids, user_ids, item_emb, user_emb,
                                                    wbf, abf);
  main_kernel<<<dim3(NVT, NBG), 512, 0, stream>>>(wbf, abf, tf_item, lens_item,
                                                  tf_user, lens_user, out);
}